// Round 9
// baseline (66.454 us; speedup 1.0000x reference)
//
#include <hip/hip_runtime.h>
#include <math.h>

// Problem constants (reference: B=4, N=2048, H=5, L=3)
#define B_ 4
#define N_ 2048
#define H_ 5
#define L_ 3
#define EPS_ 1e-6f

constexpr int WAVES = 8;               // waves per block
constexpr int THREADS = WAVES * 64;    // 512
constexpr int RPW = 4;                 // rows per wave
constexpr int RPB = RPW * WAVES;       // 32 rows per block
constexpr int CHUNKS = N_ / RPB;       // 64 chunks per (b,h)
constexpr int GRID = B_ * H_ * CHUNKS; // 1280 blocks = 5/CU exactly
constexpr int ITERS = N_ / 64;         // 32 j-elements per lane
constexpr int SIT = N_ / THREADS;      // 4 staging elements per thread
constexpr float LOG2E = 1.4426950408889634f;

// One block = one (batch, head, 32-row chunk). Heads run in PARALLEL across
// blocks (R8 ran them serially with 12 block-wide barriers/layer; this has 3).
// Previous layer's LN is folded into staging: a_prev holds w0-scaled per-head
// outputs [B,H,N]; block sums heads, computes row stats locally (no partials),
// applies LN, then stages kv for its OWN head once and runs the inner loop.
__global__ __launch_bounds__(THREADS) void attn_head_kernel(
    const float* __restrict__ res_in,   // [B,N] residual entering this layer
    const float* __restrict__ a_prev,   // [B,H,N] prev per-head out (null l=0)
    const float* __restrict__ gamma,    // [N]
    const float* __restrict__ beta,     // [N]
    const float* __restrict__ wq,       // [H,N] layer slice
    const float* __restrict__ wk,       // [H,N]
    const float* __restrict__ wv,       // [H,N]
    const float* __restrict__ w0,       // [H]
    float* __restrict__ a_out,          // [B,H,N] w0-scaled per-head out
    float* __restrict__ res_out)        // [B,N] updated residual (null l=0)
{
  __shared__ float xb[N_];      // residual row (8 KB)
  __shared__ float2 kv[N_];     // (k'_j, v_j) for this block's head (16 KB)
  __shared__ float2 red[WAVES];

  const int bid = blockIdx.x;
  const int chunk = bid % CHUNKS;
  const int h = (bid / CHUNKS) % H_;
  const int b = bid / (CHUNKS * H_);
  const int tid = threadIdx.x;
  const int wave = tid >> 6;
  const int lane = tid & 63;
  const int i0 = chunk * RPB + wave * RPW;  // this wave's first row

  // ---- Stage xb = res_in (+ LN(sum of prev heads)) ----
  if (a_prev == nullptr) {
#pragma unroll
    for (int it = 0; it < SIT; ++it) {
      const int j = tid + it * THREADS;
      xb[j] = res_in[b * N_ + j];
    }
  } else {
    const float* ap = a_prev + b * H_ * N_;
    float aj[SIT];
    float s1 = 0.f, s2 = 0.f;
#pragma unroll
    for (int it = 0; it < SIT; ++it) {
      const int j = tid + it * THREADS;
      float v = ap[j] + ap[N_ + j] + ap[2 * N_ + j] + ap[3 * N_ + j] +
                ap[4 * N_ + j];
      aj[it] = v;
      s1 += v;
      s2 = fmaf(v, v, s2);
    }
#pragma unroll
    for (int off = 32; off; off >>= 1) {
      s1 += __shfl_xor(s1, off);
      s2 += __shfl_xor(s2, off);
    }
    if (lane == 0) red[wave] = make_float2(s1, s2);
    __syncthreads();
    s1 = 0.f; s2 = 0.f;
#pragma unroll
    for (int w = 0; w < WAVES; ++w) {
      s1 += red[w].x;
      s2 += red[w].y;
    }
    const float mean = s1 * (1.f / N_);
    const float var = (s2 - s1 * mean) * (1.f / (N_ - 1));
    const float inv = 1.f / (sqrtf(var) + EPS_);
#pragma unroll
    for (int it = 0; it < SIT; ++it) {
      const int j = tid + it * THREADS;
      xb[j] = res_in[b * N_ + j] + gamma[j] * (aj[it] - mean) * inv + beta[j];
    }
  }
  __syncthreads();

  // One designated block per (b,chunk) publishes the updated residual
  if (res_out != nullptr && h == 0 && tid < RPB) {
    const int i = chunk * RPB + tid;
    res_out[b * N_ + i] = xb[i];
  }

  // ---- Stage kv for OUR head (once) + q for our rows ----
#pragma unroll
  for (int it = 0; it < SIT; ++it) {
    const int j = tid + it * THREADS;
    float oj = xb[j];
    kv[j] = make_float2(oj * wk[h * N_ + j] * LOG2E, oj * wv[h * N_ + j]);
  }
  float q[RPW];
#pragma unroll
  for (int r = 0; r < RPW; ++r) q[r] = xb[i0 + r] * wq[h * N_ + i0 + r];
  __syncthreads();

  // ---- Inner loop: 4 rows per wave, 4 independent chains ----
  float d[RPW], n[RPW];
#pragma unroll
  for (int r = 0; r < RPW; ++r) { d[r] = 0.f; n[r] = 0.f; }
#pragma unroll
  for (int it = 0; it < ITERS; ++it) {
    float2 kvj = kv[it * 64 + lane];
#pragma unroll
    for (int r = 0; r < RPW; ++r) {
      float e = __builtin_amdgcn_exp2f(q[r] * kvj.x);
      d[r] += e;
      n[r] = fmaf(e, kvj.y, n[r]);
    }
  }

  // ---- Reduce + store w0-scaled per-head output ----
  const float w0h = w0[h];
#pragma unroll
  for (int r = 0; r < RPW; ++r) {
    float dd = d[r], nn = n[r];
#pragma unroll
    for (int off = 32; off; off >>= 1) {
      dd += __shfl_xor(dd, off);
      nn += __shfl_xor(nn, off);
    }
    if (lane == 0) {
      const int i = i0 + r;
      float2 kvi = kv[i];
      float ed = __builtin_amdgcn_exp2f(q[r] * kvi.x);  // diagonal term
      a_out[(b * H_ + h) * N_ + i] =
          w0h * (nn - ed * kvi.y) * __builtin_amdgcn_rcpf(dd);
    }
  }
}

// out[b,:] = res_in + gamma*(sum_h a[h]-mean)/(sqrt(var_ub)+eps) + beta
__global__ __launch_bounds__(THREADS) void final_ln_kernel(
    const float* __restrict__ res_in,   // [B,N]
    const float* __restrict__ a_prev,   // [B,H,N]
    const float* __restrict__ gamma, const float* __restrict__ beta,
    float* __restrict__ out)
{
  __shared__ float2 red[WAVES];
  const int b = blockIdx.x;
  const int tid = threadIdx.x;
  const int wave = tid >> 6;
  const int lane = tid & 63;
  const float* ap = a_prev + b * H_ * N_;

  float aj[SIT];
  float s1 = 0.f, s2 = 0.f;
#pragma unroll
  for (int it = 0; it < SIT; ++it) {
    const int j = tid + it * THREADS;
    float v = ap[j] + ap[N_ + j] + ap[2 * N_ + j] + ap[3 * N_ + j] +
              ap[4 * N_ + j];
    aj[it] = v;
    s1 += v;
    s2 = fmaf(v, v, s2);
  }
#pragma unroll
  for (int off = 32; off; off >>= 1) {
    s1 += __shfl_xor(s1, off);
    s2 += __shfl_xor(s2, off);
  }
  if (lane == 0) red[wave] = make_float2(s1, s2);
  __syncthreads();
  s1 = 0.f; s2 = 0.f;
#pragma unroll
  for (int w = 0; w < WAVES; ++w) {
    s1 += red[w].x;
    s2 += red[w].y;
  }
  const float mean = s1 * (1.f / N_);
  const float var = (s2 - s1 * mean) * (1.f / (N_ - 1));
  const float inv = 1.f / (sqrtf(var) + EPS_);
#pragma unroll
  for (int it = 0; it < SIT; ++it) {
    const int j = tid + it * THREADS;
    out[b * N_ + j] =
        res_in[b * N_ + j] + gamma[j] * (aj[it] - mean) * inv + beta[j];
  }
}

extern "C" void kernel_launch(void* const* d_in, const int* in_sizes, int n_in,
                              void* d_out, int out_size, void* d_ws, size_t ws_size,
                              hipStream_t stream) {
  const float* x     = (const float*)d_in[0];
  const float* WQ    = (const float*)d_in[1];  // [L,H,N]
  const float* WK    = (const float*)d_in[2];
  const float* WV    = (const float*)d_in[3];
  const float* W0    = (const float*)d_in[4];  // [L,H]
  const float* gamma = (const float*)d_in[5];
  const float* beta  = (const float*)d_in[6];
  float* out = (float*)d_out;

  float* ws = (float*)d_ws;
  float* a0   = ws;                        // [B,H,N] = 40960 floats
  float* a1   = ws + 40960;
  float* a2   = ws + 2 * 40960;
  float* res1 = ws + 3 * 40960;            // [B,N]
  float* res2 = ws + 3 * 40960 + 8192;     // [B,N]

  // Layer 0: xb = x
  attn_head_kernel<<<GRID, THREADS, 0, stream>>>(
      x, nullptr, gamma, beta,
      WQ, WK, WV, W0, a0, nullptr);
  // Layer 1: xb = x + LN(sum a0) (h==0 blocks write res1)
  attn_head_kernel<<<GRID, THREADS, 0, stream>>>(
      x, a0, gamma, beta,
      WQ + H_ * N_, WK + H_ * N_, WV + H_ * N_, W0 + H_, a1, res1);
  // Layer 2: xb = res1 + LN(sum a1) (h==0 blocks write res2)
  attn_head_kernel<<<GRID, THREADS, 0, stream>>>(
      res1, a1, gamma, beta,
      WQ + 2 * H_ * N_, WK + 2 * H_ * N_, WV + 2 * H_ * N_, W0 + 2 * H_, a2, res2);
  // Final: out = res2 + LN(sum a2)
  final_ln_kernel<<<B_, THREADS, 0, stream>>>(res2, a2, gamma, beta, out);
}

// Round 10
// 38.468 us; speedup vs baseline: 1.7275x; 1.7275x over previous
//
#include <hip/hip_runtime.h>
#include <math.h>

// Problem constants (reference: B=4, N=2048, H=5, L=3)
#define B_ 4
#define N_ 2048
#define H_ 5
#define L_ 3
#define EPS_ 1e-6f

constexpr int THREADS = 256;
constexpr int WAVES = 4;
constexpr int JPT = N_ / THREADS;   // 8 elements per thread
constexpr int M_ = 21;              // Taylor terms m = 0..20
constexpr float LOG2E = 1.4426950408889634f;

// 1/m! for m=0..20
__device__ __constant__ float INV_FACT[M_] = {
    1.0f, 1.0f, 0.5f, 1.6666666666666666e-01f, 4.1666666666666664e-02f,
    8.3333333333333332e-03f, 1.3888888888888889e-03f, 1.9841269841269841e-04f,
    2.4801587301587302e-05f, 2.7557319223985893e-06f, 2.7557319223985888e-07f,
    2.5052108385441720e-08f, 2.0876756987868100e-09f, 1.6059043836821613e-10f,
    1.1470745597729725e-11f, 7.6471637318198164e-13f, 4.7794773323873853e-14f,
    2.8114572543455206e-15f, 1.5619206968586225e-16f, 8.2206352466243295e-18f,
    4.1103176233121648e-19f};

// Rank-1 factorized attention:
//   s_ij = q_i * k_j  =>  e^{s_ij} = sum_m (q_i^m/m!) k_j^m   (Taylor, M=21)
//   D_i  = sum_m (q_i^m/m!) S_m,   S_m = sum_j k_j^m
//   Num_i= sum_m (q_i^m/m!) T_m,   T_m = sum_j k_j^m v_j
//   att_i = (Num_i - e_ii*v_i) / D_i   (exact diagonal; denom keeps diag)
// O(N*M) per head instead of O(N^2) exps. One block per (b,h).
__global__ __launch_bounds__(THREADS) void attn_poly_kernel(
    const float* __restrict__ res_in,   // [B,N] residual entering this layer
    const float* __restrict__ a_prev,   // [B,H,N] prev w0-scaled heads (null l=0)
    const float* __restrict__ gamma,    // [N]
    const float* __restrict__ beta,     // [N]
    const float* __restrict__ wq,       // [H,N] layer slice
    const float* __restrict__ wk,       // [H,N]
    const float* __restrict__ wv,       // [H,N]
    const float* __restrict__ w0,       // [H]
    float* __restrict__ a_out,          // [B,H,N] w0-scaled per-head out
    float* __restrict__ res_out)        // [B,N] updated residual (null l=0)
{
  __shared__ float xb[N_];             // residual row (8 KB)
  __shared__ float red[WAVES][2 * M_]; // per-wave power-sum partials
  __shared__ float fin[2 * M_];        // S'_m (m<21), T'_m (m>=21), /m! folded
  __shared__ float2 red2[WAVES];       // LN stat partials

  const int h = blockIdx.x % H_;
  const int b = blockIdx.x / H_;
  const int tid = threadIdx.x;
  const int wave = tid >> 6;
  const int lane = tid & 63;

  // ---- Stage xb = res_in (+ LN(sum of prev heads)) ----
  if (a_prev == nullptr) {
#pragma unroll
    for (int r = 0; r < JPT; ++r) {
      const int j = tid + r * THREADS;
      xb[j] = res_in[b * N_ + j];
    }
  } else {
    const float* ap = a_prev + b * H_ * N_;
    float aj[JPT];
    float s1 = 0.f, s2 = 0.f;
#pragma unroll
    for (int r = 0; r < JPT; ++r) {
      const int j = tid + r * THREADS;
      float v = ap[j] + ap[N_ + j] + ap[2 * N_ + j] + ap[3 * N_ + j] +
                ap[4 * N_ + j];
      aj[r] = v;
      s1 += v;
      s2 = fmaf(v, v, s2);
    }
#pragma unroll
    for (int off = 32; off; off >>= 1) {
      s1 += __shfl_xor(s1, off);
      s2 += __shfl_xor(s2, off);
    }
    if (lane == 0) red2[wave] = make_float2(s1, s2);
    __syncthreads();
    s1 = red2[0].x + red2[1].x + red2[2].x + red2[3].x;
    s2 = red2[0].y + red2[1].y + red2[2].y + red2[3].y;
    const float mean = s1 * (1.f / N_);
    const float var = (s2 - s1 * mean) * (1.f / (N_ - 1));
    const float inv = 1.f / (sqrtf(var) + EPS_);
#pragma unroll
    for (int r = 0; r < JPT; ++r) {
      const int j = tid + r * THREADS;
      xb[j] = res_in[b * N_ + j] + gamma[j] * (aj[r] - mean) * inv + beta[j];
    }
  }
  __syncthreads();

  // h==0 block publishes the updated residual for the next dispatch
  if (res_out != nullptr && h == 0) {
#pragma unroll
    for (int r = 0; r < JPT; ++r) {
      const int j = tid + r * THREADS;
      res_out[b * N_ + j] = xb[j];
    }
  }

  // ---- Power sums S_m, T_m over this head's k,v ----
  const float* wkh = wk + h * N_;
  const float* wvh = wv + h * N_;
  float kj[JPT], vj[JPT];   // kept for exact diagonal in row phase (i==j map)
  float S[M_], T[M_];
#pragma unroll
  for (int m = 0; m < M_; ++m) { S[m] = 0.f; T[m] = 0.f; }
#pragma unroll
  for (int r = 0; r < JPT; ++r) {
    const int j = tid + r * THREADS;
    const float xv = xb[j];
    kj[r] = xv * wkh[j];
    vj[r] = xv * wvh[j];
    float p = 1.f;
#pragma unroll
    for (int m = 0; m < M_; ++m) {
      S[m] += p;
      T[m] = fmaf(p, vj[r], T[m]);
      p *= kj[r];
    }
  }
  // Reduce 42 values: wave butterfly -> LDS -> 42 threads combine (+ /m!)
#pragma unroll
  for (int m = 0; m < M_; ++m) {
#pragma unroll
    for (int off = 32; off; off >>= 1) {
      S[m] += __shfl_xor(S[m], off);
      T[m] += __shfl_xor(T[m], off);
    }
    if (lane == 0) {
      red[wave][m] = S[m];
      red[wave][M_ + m] = T[m];
    }
  }
  __syncthreads();
  if (tid < 2 * M_) {
    float f = red[0][tid] + red[1][tid] + red[2][tid] + red[3][tid];
    fin[tid] = f * INV_FACT[tid < M_ ? tid : tid - M_];
  }
  __syncthreads();

  // Hoist folded sums into registers (reused across JPT rows)
  float Sf[M_], Tf[M_];
#pragma unroll
  for (int m = 0; m < M_; ++m) {
    Sf[m] = fin[m];
    Tf[m] = fin[M_ + m];
  }

  // ---- Row phase: polynomial evaluation per row ----
  const float* wqh = wq + h * N_;
  const float w0h = w0[h];
#pragma unroll
  for (int r = 0; r < JPT; ++r) {
    const int i = tid + r * THREADS;
    const float q = xb[i] * wqh[i];
    float d = 0.f, n = 0.f, pq = 1.f;
#pragma unroll
    for (int m = 0; m < M_; ++m) {
      d = fmaf(pq, Sf[m], d);
      n = fmaf(pq, Tf[m], n);
      pq *= q;
    }
    const float eii = __builtin_amdgcn_exp2f(q * kj[r] * LOG2E);
    const float att = (n - eii * vj[r]) * __builtin_amdgcn_rcpf(d);
    a_out[(b * H_ + h) * N_ + i] = w0h * att;
  }
}

// out[b,:] = res_in + gamma*(sum_h a[h]-mean)/(sqrt(var_ub)+eps) + beta
__global__ __launch_bounds__(THREADS) void final_ln_kernel(
    const float* __restrict__ res_in,   // [B,N]
    const float* __restrict__ a_prev,   // [B,H,N]
    const float* __restrict__ gamma, const float* __restrict__ beta,
    float* __restrict__ out)
{
  __shared__ float2 red2[WAVES];
  const int b = blockIdx.x;
  const int tid = threadIdx.x;
  const int wave = tid >> 6;
  const int lane = tid & 63;
  const float* ap = a_prev + b * H_ * N_;

  float aj[JPT];
  float s1 = 0.f, s2 = 0.f;
#pragma unroll
  for (int r = 0; r < JPT; ++r) {
    const int j = tid + r * THREADS;
    float v = ap[j] + ap[N_ + j] + ap[2 * N_ + j] + ap[3 * N_ + j] +
              ap[4 * N_ + j];
    aj[r] = v;
    s1 += v;
    s2 = fmaf(v, v, s2);
  }
#pragma unroll
  for (int off = 32; off; off >>= 1) {
    s1 += __shfl_xor(s1, off);
    s2 += __shfl_xor(s2, off);
  }
  if (lane == 0) red2[wave] = make_float2(s1, s2);
  __syncthreads();
  s1 = red2[0].x + red2[1].x + red2[2].x + red2[3].x;
  s2 = red2[0].y + red2[1].y + red2[2].y + red2[3].y;
  const float mean = s1 * (1.f / N_);
  const float var = (s2 - s1 * mean) * (1.f / (N_ - 1));
  const float inv = 1.f / (sqrtf(var) + EPS_);
#pragma unroll
  for (int r = 0; r < JPT; ++r) {
    const int j = tid + r * THREADS;
    out[b * N_ + j] =
        res_in[b * N_ + j] + gamma[j] * (aj[r] - mean) * inv + beta[j];
  }
}

extern "C" void kernel_launch(void* const* d_in, const int* in_sizes, int n_in,
                              void* d_out, int out_size, void* d_ws, size_t ws_size,
                              hipStream_t stream) {
  const float* x     = (const float*)d_in[0];
  const float* WQ    = (const float*)d_in[1];  // [L,H,N]
  const float* WK    = (const float*)d_in[2];
  const float* WV    = (const float*)d_in[3];
  const float* W0    = (const float*)d_in[4];  // [L,H]
  const float* gamma = (const float*)d_in[5];
  const float* beta  = (const float*)d_in[6];
  float* out = (float*)d_out;

  float* ws = (float*)d_ws;
  float* a0   = ws;                        // [B,H,N] = 40960 floats each
  float* a1   = ws + 40960;
  float* a2   = ws + 2 * 40960;
  float* res1 = ws + 3 * 40960;            // [B,N]
  float* res2 = ws + 3 * 40960 + 8192;     // [B,N]

  const int G = B_ * H_;  // 20 blocks

  // Layer 0: xb = x
  attn_poly_kernel<<<G, THREADS, 0, stream>>>(
      x, nullptr, gamma, beta,
      WQ, WK, WV, W0, a0, nullptr);
  // Layer 1: xb = x + LN(sum a0)  (h==0 blocks write res1)
  attn_poly_kernel<<<G, THREADS, 0, stream>>>(
      x, a0, gamma, beta,
      WQ + H_ * N_, WK + H_ * N_, WV + H_ * N_, W0 + H_, a1, res1);
  // Layer 2: xb = res1 + LN(sum a1)  (h==0 blocks write res2)
  attn_poly_kernel<<<G, THREADS, 0, stream>>>(
      res1, a1, gamma, beta,
      WQ + 2 * H_ * N_, WK + 2 * H_ * N_, WV + 2 * H_ * N_, W0 + 2 * H_, a2, res2);
  // Final: out = res2 + LN(sum a2)
  final_ln_kernel<<<B_, THREADS, 0, stream>>>(res2, a2, gamma, beta, out);
}